// Round 7
// baseline (629.211 us; speedup 1.0000x reference)
//
#include <hip/hip_runtime.h>
#include <hip/hip_bf16.h>
#include <stdint.h>

typedef _Float16 half8 __attribute__((ext_vector_type(8)));
typedef _Float16 half4v __attribute__((ext_vector_type(4)));
typedef float f32x4 __attribute__((ext_vector_type(4)));

#define T_STEPS 20
#define B_SZ 512
#define D_IN 4096
#define H_SZ 1024
#define C_SZ 100
#define M_TOT (T_STEPS * B_SZ)  // 10240
#define BK 32
#define KITERS (D_IN / BK)  // 128

// LDS strides for prep transpose (f16 units): bank-staggered
#define PQ 136   // q-block stride (128 + 8 pad)
#define PKI 560  // ki-block stride (4*136 + 16 pad) -> +24 banks per ki

// ---------- helpers ----------
__device__ __forceinline__ void gload16(const _Float16* g, _Float16* l) {
  __builtin_amdgcn_global_load_lds(
      (const __attribute__((address_space(1))) void*)g,
      (__attribute__((address_space(3))) void*)l, 16, 0, 0);
}

struct HL4 {
  half4v h;
  half4v l;
};
__device__ __forceinline__ HL4 split4(float4 a) {
  HL4 r;
  auto p0 = __builtin_amdgcn_cvt_pkrtz(a.x, a.y);
  auto p1 = __builtin_amdgcn_cvt_pkrtz(a.z, a.w);
  r.h.x = p0.x; r.h.y = p0.y; r.h.z = p1.x; r.h.w = p1.y;
  auto q0 = __builtin_amdgcn_cvt_pkrtz(a.x - (float)p0.x, a.y - (float)p0.y);
  auto q1 = __builtin_amdgcn_cvt_pkrtz(a.z - (float)p1.x, a.w - (float)p1.y);
  r.l.x = q0.x; r.l.y = q0.y; r.l.z = q1.x; r.l.w = q1.y;
  return r;
}

// ---------- prep: fp32 row-major -> fp16 hi/lo planes in fragment-tile order ----
// R6 suspect: (ki, rt)-gridded prep read 128-B segments at 16-KB stride. Now:
// block (rt, fb) owns 16 CONSECUTIVE rows; per 512-col window, reads are fully
// coalesced float4 streams; LDS transpose (bank-staggered, worst 2-way = free);
// writes are 1-KB contiguous bursts in fragment order. Blocks 704.. handle W2.
__global__ __launch_bounds__(256) void k_prep(
    const float* __restrict__ Z, _Float16* __restrict__ Azh, _Float16* __restrict__ Azl,
    const float* __restrict__ W1, _Float16* __restrict__ Wfh, _Float16* __restrict__ Wfl,
    const float* __restrict__ W2, _Float16* __restrict__ W2h, _Float16* __restrict__ W2l) {
  const int bid = blockIdx.x;
  const int tid = threadIdx.x;

  if (bid >= 704) {  // W2 pad+split: 112*1024 elems over 64 blocks
    const int base = (bid - 704) * 1792;
#pragma unroll
    for (int i = 0; i < 7; ++i) {
      const int idx = base + i * 256 + tid;
      float v = (idx < C_SZ * H_SZ) ? W2[idx] : 0.0f;
      _Float16 h = (_Float16)v;
      W2h[idx] = h;
      W2l[idx] = (_Float16)(v - (float)h);
    }
    return;
  }

  int rt = bid >> 3;
  const int fb = bid & 7;
  const float* src;
  _Float16 *dh, *dl;
  if (rt < 80) {
    src = Z; dh = Azh; dl = Azl;
  } else {
    rt -= 80; src = W1; dh = Wfh; dl = Wfl;
  }
  const float* rowbase = src + (int64_t)(rt * 128 + fb * 16) * D_IN;

  __shared__ _Float16 sH[16 * PKI];  // 16 ki-blocks per window
  __shared__ _Float16 sL[16 * PKI];

  for (int win = 0; win < 8; ++win) {
    // Phase A: coalesced read + convert + LDS write (fragment position)
#pragma unroll
    for (int it = 0; it < 8; ++it) {
      const int idx = it * 256 + tid;      // float4 index in 16x512 tile
      const int r = idx >> 7;              // row 0..15
      const int c4 = idx & 127;            // float4 col
      const int col = c4 * 4;
      float4 v = *(const float4*)(rowbase + (int64_t)r * D_IN + win * 512 + col);
      HL4 hl = split4(v);
      const int ki_l = col >> 5;
      const int q = (col >> 3) & 3;
      const int k4 = col & 7;  // 0 or 4
      const int d = ki_l * PKI + q * PQ + r * 8 + k4;
      *(half4v*)&sH[d] = hl.h;
      *(half4v*)&sL[d] = hl.l;
    }
    __syncthreads();
    // Phase B: LDS read (fragment order) -> 1-KB contiguous global bursts
#pragma unroll
    for (int it = 0; it < 4; ++it) {
      const int o = it * 256 + tid;        // octet 0..1023
      const int ki_l = o >> 6;
      const int j = o & 63;                // q*16 + r
      const int q = j >> 4;
      const int r = j & 15;
      const int sidx = ki_l * PKI + q * PQ + r * 8;
      const int ki = win * 16 + ki_l;
      const int64_t d = (((int64_t)rt * 128 + ki) * 8 + fb) * 512 + j * 8;
      *(half8*)&dh[d] = *(const half8*)&sH[sidx];
      *(half8*)&dl[d] = *(const half8*)&sL[sidx];
    }
    __syncthreads();
  }
}

// ---------- big GEMM + fused BN partial stats ----------
// R2/m97 2-barrier structure (R6: 259 us, MfmaUtil 46%, 0 conflicts). Epilogue
// additionally shuffle-reduces per-column sum/sumsq and atomicAdds into
// Ssum/Ssq[20][1024] (8 adders per slot, device-scope f32 atomics).
__global__ __launch_bounds__(256) void k_gemm1(
    const _Float16* __restrict__ Ahi, const _Float16* __restrict__ Alo,
    const _Float16* __restrict__ Whi, const _Float16* __restrict__ Wlo,
    float* __restrict__ Hbuf, float* __restrict__ Ssum, float* __restrict__ Ssq) {
  __shared__ _Float16 sAh[4096];
  __shared__ _Float16 sAl[4096];
  __shared__ _Float16 sWh[4096];
  __shared__ _Float16 sWl[4096];

  const int tid = threadIdx.x;
  const int lane = tid & 63;
  const int w = tid >> 6;

  const int bid = blockIdx.x;          // XCD-band swizzle (R2: FETCH 957->185 MB)
  const int xcd = bid & 7;
  const int q = bid >> 3;
  const int mt = xcd * 10 + (q >> 3);
  const int nt = q & 7;

  const int ls = w * 512 + lane * 8;
  const _Float16* gAh = Ahi + (int64_t)mt * (128 * 4096) + ls;
  const _Float16* gAl = Alo + (int64_t)mt * (128 * 4096) + ls;
  const _Float16* gWh = Whi + (int64_t)nt * (128 * 4096) + ls;
  const _Float16* gWl = Wlo + (int64_t)nt * (128 * 4096) + ls;

  const int wm = (w >> 1) * 64;
  const int wn = (w & 1) * 64;
  const int ra = (wm >> 4) * 512 + lane * 8;
  const int rb = (wn >> 4) * 512 + lane * 8;
  const int fr = lane & 15;
  const int quad = lane >> 4;

  f32x4 acc[4][4] = {};

  for (int ki = 0; ki < KITERS; ++ki) {
    const int64_t so = (int64_t)ki * 4096;
    __syncthreads();
    gload16(gAh + so, &sAh[ls]);
    gload16(gAh + so + 2048, &sAh[ls + 2048]);
    gload16(gAl + so, &sAl[ls]);
    gload16(gAl + so + 2048, &sAl[ls + 2048]);
    gload16(gWh + so, &sWh[ls]);
    gload16(gWh + so + 2048, &sWh[ls + 2048]);
    gload16(gWl + so, &sWl[ls]);
    gload16(gWl + so + 2048, &sWl[ls + 2048]);
    __syncthreads();

    half8 ah[4], al[4], bh[4], bl[4];
#pragma unroll
    for (int i = 0; i < 4; ++i) {
      ah[i] = *(const half8*)&sAh[ra + i * 512];
      al[i] = *(const half8*)&sAl[ra + i * 512];
      bh[i] = *(const half8*)&sWh[rb + i * 512];
      bl[i] = *(const half8*)&sWl[rb + i * 512];
    }
#pragma unroll
    for (int a = 0; a < 4; ++a) {
#pragma unroll
      for (int b = 0; b < 4; ++b) {
        acc[a][b] = __builtin_amdgcn_mfma_f32_16x16x32_f16(ah[a], bh[b], acc[a][b], 0, 0, 0);
        acc[a][b] = __builtin_amdgcn_mfma_f32_16x16x32_f16(ah[a], bl[b], acc[a][b], 0, 0, 0);
        acc[a][b] = __builtin_amdgcn_mfma_f32_16x16x32_f16(al[a], bh[b], acc[a][b], 0, 0, 0);
      }
    }
  }

  // epilogue: C/D layout col=lane&15, row=quad*4+reg
  const int64_t m0 = (int64_t)mt * 128;
  const int64_t n0 = (int64_t)nt * 128;
#pragma unroll
  for (int a = 0; a < 4; ++a) {
#pragma unroll
    for (int r = 0; r < 4; ++r) {
      const int64_t row = m0 + wm + a * 16 + quad * 4 + r;
      float* dst = Hbuf + row * H_SZ + n0 + wn + fr;
#pragma unroll
      for (int b = 0; b < 4; ++b) dst[b * 16] = acc[a][b][r];
    }
  }

  // fused BN partial stats: per wave, col = n0+wn+fr+b*16, rows wm..wm+63
  const int t = mt >> 2;  // 128-row tile lies within one timestep (512 rows)
#pragma unroll
  for (int b = 0; b < 4; ++b) {
    float s = 0.f, s2 = 0.f;
#pragma unroll
    for (int a = 0; a < 4; ++a)
#pragma unroll
      for (int r = 0; r < 4; ++r) {
        float v = acc[a][b][r];
        s += v;
        s2 += v * v;
      }
    s += __shfl_xor(s, 16);  s2 += __shfl_xor(s2, 16);
    s += __shfl_xor(s, 32);  s2 += __shfl_xor(s2, 32);
    if (quad == 0) {
      const int h = (int)n0 + wn + fr + b * 16;
      atomicAdd(&Ssum[t * H_SZ + h], s);
      atomicAdd(&Ssq[t * H_SZ + h], s2);
    }
  }
}

// ---------- LIF recurrence per (b,h): scale/shift inline, spike count S ----------
__global__ void k_recur(const float* __restrict__ Hbuf, const float* __restrict__ Ssum,
                        const float* __restrict__ Ssq, const float* __restrict__ gamma,
                        _Float16* __restrict__ S) {
  const int idx = blockIdx.x * 256 + threadIdx.x;
  const int b = idx >> 10;
  const int h = idx & 1023;
  float mem = 0.f;
  int cnt = 0;
#pragma unroll
  for (int t = 0; t < T_STEPS; ++t) {
    const float mean = Ssum[(t << 10) + h] * (1.0f / B_SZ);
    const float var = Ssq[(t << 10) + h] * (1.0f / B_SZ) - mean * mean;
    const float sc = gamma[(t << 10) + h] * rsqrtf(var + 1e-4f);
    float v = Hbuf[((int64_t)(t * B_SZ + b) << 10) + h];
    v = (v - mean) * sc;
    mem = 0.95f * mem + v;
    if (mem - 1.0f > 0.0f) {
      ++cnt;
      mem -= 1.0f;
    }
  }
  S[idx] = (_Float16)cnt;
}

// ---------- GEMM2: out = S @ W2^T / 20, 2-term fp16 split (exact: S integer) ----------
__global__ void k_gemm2(const _Float16* __restrict__ S, const _Float16* __restrict__ W2h,
                        const _Float16* __restrict__ W2l, float* __restrict__ out) {
  const int wid = threadIdx.x >> 6;
  const int lane = threadIdx.x & 63;
  const int m0 = blockIdx.y * 64 + wid * 16;
  const int n0 = blockIdx.x * 16;
  const int fr = lane & 15;
  const int quad = lane >> 4;

  const _Float16* sp = S + (int64_t)(m0 + fr) * H_SZ + quad * 8;
  const _Float16* wph = W2h + (int64_t)(n0 + fr) * H_SZ + quad * 8;
  const _Float16* wpl = W2l + (int64_t)(n0 + fr) * H_SZ + quad * 8;

  f32x4 acc = {0.f, 0.f, 0.f, 0.f};
#pragma unroll 4
  for (int k = 0; k < H_SZ; k += 32) {
    half8 a = *(const half8*)(sp + k);
    half8 bh = *(const half8*)(wph + k);
    half8 bl = *(const half8*)(wpl + k);
    acc = __builtin_amdgcn_mfma_f32_16x16x32_f16(a, bh, acc, 0, 0, 0);
    acc = __builtin_amdgcn_mfma_f32_16x16x32_f16(a, bl, acc, 0, 0, 0);
  }
  const int col = n0 + fr;
  if (col < C_SZ) {
#pragma unroll
    for (int r = 0; r < 4; ++r) {
      const int row = m0 + quad * 4 + r;
      out[row * C_SZ + col] = acc[r] * (1.0f / T_STEPS);
    }
  }
}

extern "C" void kernel_launch(void* const* d_in, const int* in_sizes, int n_in,
                              void* d_out, int out_size, void* d_ws, size_t ws_size,
                              hipStream_t stream) {
  const float* z = (const float*)d_in[0];      // [20,512,4096]
  const float* W1 = (const float*)d_in[1];     // [1024,4096]
  const float* gamma = (const float*)d_in[2];  // [20,1024]
  const float* W2 = (const float*)d_in[3];     // [100,1024]
  float* out = (float*)d_out;                  // [512,100]

  char* ws = (char*)d_ws;
  size_t off = 0;
  auto alloc = [&](size_t bytes) -> void* {
    void* p = ws + off;
    off += (bytes + 255) & ~(size_t)255;
    return p;
  };
  _Float16* Azh = (_Float16*)alloc((size_t)M_TOT * D_IN * 2);
  _Float16* Azl = (_Float16*)alloc((size_t)M_TOT * D_IN * 2);
  _Float16* Wfh = (_Float16*)alloc((size_t)H_SZ * D_IN * 2);
  _Float16* Wfl = (_Float16*)alloc((size_t)H_SZ * D_IN * 2);
  float* Hbuf = (float*)alloc((size_t)M_TOT * H_SZ * 4);
  float* Ssum = (float*)alloc((size_t)T_STEPS * H_SZ * 4);
  float* Ssq = (float*)alloc((size_t)T_STEPS * H_SZ * 4);
  _Float16* S = (_Float16*)alloc((size_t)B_SZ * H_SZ * 2);
  _Float16* W2h = (_Float16*)alloc((size_t)112 * H_SZ * 2);
  _Float16* W2l = (_Float16*)alloc((size_t)112 * H_SZ * 2);

  // 0) zero the BN accumulators (re-poisoned to 0xAA before every call)
  hipMemsetAsync(Ssum, 0, (size_t)2 * T_STEPS * H_SZ * 4, stream);

  // 1) z + W1 -> fragment-tiled fp16 hi/lo planes; W2 hi/lo (folded in)
  k_prep<<<768, 256, 0, stream>>>(z, Azh, Azl, W1, Wfh, Wfl, W2, W2h, W2l);

  // 2) batched fc1 GEMM + fused BN partial sums
  k_gemm1<<<640, 256, 0, stream>>>(Azh, Azl, Wfh, Wfl, Hbuf, Ssum, Ssq);

  // 3) LIF recurrence (scale/shift inline) -> spike counts
  k_recur<<<(B_SZ * H_SZ) / 256, 256, 0, stream>>>(Hbuf, Ssum, Ssq, gamma, S);

  // 4) spike-count GEMM -> output
  dim3 g2(7, 8);
  k_gemm2<<<g2, 256, 0, stream>>>(S, W2h, W2l, out);
}